// Round 10
// baseline (169.101 us; speedup 1.0000x reference)
//
#include <hip/hip_runtime.h>
#include <float.h>

// Problem constants (fixed by reference: B=8, D=64, H=64, W=64, K=8192)
constexpr int KCODES = 8192;
constexpr int DDIM   = 64;
constexpr int NTOK   = 32768;
constexpr int MT     = 64;                 // tokens per screen-WG (4 sets x 16)
constexpr int NSETS  = MT / 16;            // 4
constexpr int KC     = 64;                 // codes per chunk
constexpr int NCH    = KCODES / KC;        // 128 chunks
constexpr int CBCHUNK = KC * DDIM * 2;     // 8192 B (64 codes x 64 d x bf16, hi only)

constexpr int RQ    = 4;                   // LDS staging ring depth (per wave)
constexpr int ASLOT = 2048;                // per-wave A-frag bytes per chunk
constexpr int NCELL = 16;                  // 4 waves x 4 quads
constexpr int NWG   = NTOK / MT;           // 512 screen WGs

typedef short v8s __attribute__((ext_vector_type(8)));
typedef float v4f __attribute__((ext_vector_type(4)));

static __device__ __forceinline__ unsigned short f2bf(float f) {
  union { float f; unsigned u; } v; v.f = f;
  return (unsigned short)((v.u + 0x7fffu + ((v.u >> 16) & 1u)) >> 16);  // RNE
}

// async global->LDS DMA: dest = wave-uniform LDS base + lane*16 (m104);
// source is per-lane. Tracked by vmcnt.
static __device__ __forceinline__ void dma16(const void* g, void* l) {
  __builtin_amdgcn_global_load_lds(
      (const __attribute__((address_space(1))) void*)g,
      (__attribute__((address_space(3))) void*)l, 16, 0, 0);
}

// ---- fused prep: bf16 hi codebook, FRAGMENT-LINEAR for mfma_16x16x32_bf16
// A-operand (A[m=lane&15][k=(lane>>4)*8+j]), + biased half-norms
// hn[k] = 0.5*||c_k||^2 + 2.0 (bias keeps phase-1 scores positive -> fp32
// bit pattern monotone for the packed-key argmin; scores land in [~0.7,~4.5]).
// Per chunk c: byte off = c*8192 + g*2048 + ks*1024 + lane*16 + j*2.
// Grid 256 x 128 threads (2 blocks per chunk): full-device fill.
__global__ __launch_bounds__(128) void prep_kernel(
    const float* __restrict__ cb, unsigned short* __restrict__ wcb,
    float* __restrict__ hn) {
  const int c = blockIdx.x >> 1;            // chunk 0..127
  const int tid = threadIdx.x;
  const int g = ((blockIdx.x & 1) << 1) | (tid >> 6);   // 16-code group 0..3
  const int lane = tid & 63;
  const int quad = lane >> 4, col = lane & 15;
  const int code = c * KC + g * 16 + col;
  const float* src = cb + (size_t)code * DDIM;
  float sq = 0.f;
#pragma unroll
  for (int ks = 0; ks < 2; ++ks) {
    v8s hi;
#pragma unroll
    for (int j = 0; j < 8; ++j) {
      const float x = src[ks * 32 + quad * 8 + j];
      sq += x * x;
      hi[j] = (short)f2bf(x);
    }
    const size_t b0 = ((size_t)c * CBCHUNK + g * 2048 + ks * 1024 + lane * 16) / 2;
    *reinterpret_cast<v8s*>(wcb + b0) = hi;
  }
  sq += __shfl_xor(sq, 16);
  sq += __shfl_xor(sq, 32);
  if (quad == 0) hn[code] = 0.5f * sq + 2.0f;
}

// SCREEN kernel: EXACTLY round-3's measured-best loop (84 µs incl. its
// epilogue): MT=64, per-wave LDS ring depth 4, 2 dma16/chunk, counted
// s_waitcnt vmcnt(6), hn staged once into LDS, 2 WG/CU (8 waves/CU).
// Difference: NO phase-2 epilogue — the per-(lane,set)-cell packed top-2
// keys are written straight to a 4 MB global workspace. This splits the
// kernel so rocprof attributes screen-loop time vs finish time separately
// (every in-loop lever R1-R9 was null; the carried-verbatim serial
// 1-wave divergent refine epilogue is the un-ablated suspect).
//   Screening error e = xl.c + xh.cl: RMS ~2.5e-4, |e| <= ~2.8e-3 at 11
//   sigma. Branchless packed-key top-2 per (lane,set) cell: key =
//   (score-bits & ~511) | (it*4 + r); floor quantization <= 512 ulp <= 2.4e-4.
__global__ __launch_bounds__(256, 2) void screen_kernel(
    const float* __restrict__ ze, const float* __restrict__ hn,
    const unsigned short* __restrict__ wcb, unsigned* __restrict__ keys) {
  // LDS map: [0,32768) per-wave staging ring; [32768,65536) static hn copy.
  __shared__ __align__(16) char smem[65536];

  const int tid = threadIdx.x, lane = tid & 63, wv = tid >> 6;
  const int col = lane & 15, quad = lane >> 4;
  const int t0 = blockIdx.x * MT;
  const int bb = t0 >> 12, hw0 = t0 & 4095;   // 4096 % 64 == 0: one batch per WG
  const float* zb = ze + (size_t)bb * (DDIM * 4096) + hw0;

  // ---- one-time hn -> LDS copy (32 KB, 8 x float4 per thread) ----
  {
    v4f* dst = (v4f*)(smem + 32768);
    const v4f* src = (const v4f*)hn;
#pragma unroll
    for (int i = 0; i < 8; ++i) dst[tid + i * 256] = src[tid + i * 256];
  }

  // ---- B-frags: 4 sets x 16 tokens, negated bf16-hi, in registers.
  // B[k=(lane>>4)*8+j][n=lane&15]; token = s*16 + col; d = ks*32 + quad*8 + j.
  v8s nxh[NSETS][2];
#pragma unroll
  for (int s = 0; s < NSETS; ++s) {
    const int mtok = s * 16 + col;
#pragma unroll
    for (int ks = 0; ks < 2; ++ks) {
#pragma unroll
      for (int j = 0; j < 8; ++j) {
        const int d = ks * 32 + quad * 8 + j;
        nxh[s][ks][j] = (short)f2bf(-zb[(size_t)d * 4096 + mtok]);
      }
    }
  }

  char* wbase = smem + wv * (RQ * ASLOT);
  const char* wsrc = (const char*)wcb + wv * 2048 + lane * 16;
  const char* hns  = smem + 32768 + wv * 64 + quad * 16;  // this cell's hv

  auto stage = [&](int chunk, int slot) {
    const char* src = wsrc + (size_t)chunk * CBCHUNK;
    char* dst = wbase + slot * ASLOT;
    dma16(src, dst);
    dma16(src + 1024, dst + 1024);
  };

  unsigned m1[NSETS] = {0xFFFFFFFFu, 0xFFFFFFFFu, 0xFFFFFFFFu, 0xFFFFFFFFu};
  unsigned m2[NSETS] = {0xFFFFFFFFu, 0xFFFFFFFFu, 0xFFFFFFFFu, 0xFFFFFFFFu};

  auto compute = [&](const v8s (&A)[2], const v4f hv, int it) {
    const unsigned base9 = (unsigned)(it * 4);   // 9-bit cell-local index base
#pragma unroll
    for (int s = 0; s < NSETS; ++s) {            // 4 independent MFMA chains
      v4f acc = __builtin_amdgcn_mfma_f32_16x16x32_bf16(A[0], nxh[s][0], hv, 0, 0, 0);
      acc = __builtin_amdgcn_mfma_f32_16x16x32_bf16(A[1], nxh[s][1], acc, 0, 0, 0);
      unsigned k0 = (__float_as_uint(acc[0]) & ~511u) | (base9 + 0);
      unsigned k1 = (__float_as_uint(acc[1]) & ~511u) | (base9 + 1);
      unsigned k2 = (__float_as_uint(acc[2]) & ~511u) | (base9 + 2);
      unsigned k3 = (__float_as_uint(acc[3]) & ~511u) | (base9 + 3);
      const unsigned km = min(min(k0, k1), min(k2, k3));
      const unsigned old1 = m1[s];
      m1[s] = min(old1, km);
      m2[s] = min(m2[s], max(old1, km));   // branchless 2nd-best
    }
  };

  // hn LDS writes visible to all waves before any in-loop hv read.
  __syncthreads();

  // ---- airtight vmcnt ledger: drain prologue loads before first stage.
  asm volatile("s_waitcnt vmcnt(0)" ::: "memory");
  __builtin_amdgcn_sched_barrier(0);

#pragma unroll
  for (int r = 0; r < RQ; ++r) stage(r, r);   // 8 DMAs in flight (chunks 0..3)

  int sl = 0;
  for (int it = 0; it < NCH; ++it) {
    // Chunk it's 2 DMAs landed once <= 6 remain outstanding (in-order).
    asm volatile("s_waitcnt vmcnt(6)" ::: "memory");
    __builtin_amdgcn_sched_barrier(0);

    v8s A[2]; v4f hv;
    {
      const char* b = wbase + sl * ASLOT;
      A[0] = *reinterpret_cast<const v8s*>(b + lane * 16);
      A[1] = *reinterpret_cast<const v8s*>(b + 1024 + lane * 16);
      hv   = *reinterpret_cast<const v4f*>(hns + (size_t)it * 256);
    }
    compute(A, hv, it);

    // ds_reads of this slot fully retired before the DMA overwrite lands.
    asm volatile("s_waitcnt lgkmcnt(0)" ::: "memory");
    __builtin_amdgcn_sched_barrier(0);
    stage((it + RQ) & (NCH - 1), sl);   // tail wrap: redundant, never read
    sl = (sl == RQ - 1) ? 0 : sl + 1;
  }

  // Drain wrap-staged DMAs before the WG (and its LDS) retires.
  asm volatile("s_waitcnt vmcnt(0)" ::: "memory");

  // ---- write per-cell top-2 keys to workspace ----
  // keys[wg][cell][h][m]: wg-major, 16 cells, h in {0,1}, m = token 0..63.
  {
    const int cell = wv * 4 + quad;
    unsigned* kb = keys + (((size_t)blockIdx.x * NCELL + cell) * 2) * MT;
#pragma unroll
    for (int s = 0; s < NSETS; ++s) {
      const int m = s * 16 + col;
      kb[m]      = m1[s];
      kb[MT + m] = m2[s];
    }
  }
}

// FINISH kernel: 1 token per THREAD (full device parallelism for the
// formerly 1-wave-per-WG serial epilogue). Reads the 32 packed keys,
// fast-path or numpy-faithful refine, writes z_q.
//   Fast path when unique candidate within smin+8e-3. Proof: for any
//   candidate with stored > lim: true > stored - e > smin + 8e-3 - 2.8e-3;
//   smin >= true_min - e - 2.4e-4 -> true - true_min > 8e-3 - 5.6e-3 -
//   2.4e-4 > 2e-3 >> numpy's ulp(64) ~1.5e-5 quantization -> numpy cannot
//   prefer it. A numpy-winner distinct from the approx winner is itself
//   within lim -> cnt >= 2 -> refine. Refine = numpy-fp32-faithful decision
//   (pairwise-8 sums, D=fl(fl(S-2p)+N), correctly-rounded-fp64 p,
//   tie -> lowest index) — identical to all passing rounds.
//   Key decode: code = ((K&511)>>2)*64 + (c>>2)*16 + (c&3)*4 + (K&3)
//   (matches screen encode: cell c = wv*4+quad, local = it*4+r).
__global__ __launch_bounds__(256) void finish_kernel(
    const float* __restrict__ ze, const float* __restrict__ cb,
    const unsigned* __restrict__ keys, float* __restrict__ out) {
#pragma clang fp contract(off)   // numpy: separate mul then add; no FMA
  const int tk = blockIdx.x * 256 + threadIdx.x;   // token 0..32767
  const int wg = tk >> 6, m = tk & 63;
  const unsigned* kb = keys + (size_t)wg * (NCELL * 2 * MT);

  unsigned K[NCELL][2];
#pragma unroll
  for (int c = 0; c < NCELL; ++c) {
    K[c][0] = kb[(c * 2 + 0) * MT + m];
    K[c][1] = kb[(c * 2 + 1) * MT + m];
  }

  float smin = FLT_MAX; int fidx = 0x7fffffff;
#pragma unroll
  for (int c = 0; c < NCELL; ++c) {
    const float a = __uint_as_float(K[c][0] & ~511u);
    if (a < smin) {
      smin = a;
      fidx = (int)((K[c][0] & 511u) >> 2) * KC + (c >> 2) * 16 + (c & 3) * 4 +
             (int)(K[c][0] & 3u);
    }
  }
  const float lim = smin + 8e-3f;   // covers 2*e_screen(2.8e-3) + key floor
                                    // 2.4e-4 + numpy noise, ~1.4x slack
  int cnt = 0;
#pragma unroll
  for (int c = 0; c < NCELL; ++c) {
    cnt += (__uint_as_float(K[c][0] & ~511u) <= lim);
    cnt += (__uint_as_float(K[c][1] & ~511u) <= lim);
  }

  int besti;
  if (cnt == 1) {
    besti = fidx;   // unique in-margin candidate: approx argmin == numpy argmin
  } else {
    const float* xz = ze + (size_t)(tk >> 12) * (DDIM * 4096) + (tk & 4095);
    float xm[DDIM];
    for (int d = 0; d < DDIM; ++d) xm[d] = xz[(size_t)d * 4096];

    float r[8];
    for (int j = 0; j < 8; ++j) r[j] = xm[j] * xm[j];
    for (int i = 8; i < DDIM; i += 8)
      for (int j = 0; j < 8; ++j) r[j] += xm[i + j] * xm[i + j];
    const float S = ((r[0] + r[1]) + (r[2] + r[3])) + ((r[4] + r[5]) + (r[6] + r[7]));

    float bestD = FLT_MAX;
    besti = 0x7fffffff;
    for (int c = 0; c < NCELL; ++c) {
      for (int h = 0; h < 2; ++h) {
        const unsigned Kc = K[c][h];
        const float sp = __uint_as_float(Kc & ~511u);
        if (sp > lim) continue;
        const int idx = (int)((Kc & 511u) >> 2) * KC + (c >> 2) * 16 + (c & 3) * 4 +
                        (int)(Kc & 3u);
        const float* crow = cb + (size_t)idx * DDIM;

        float rn[8];
        for (int j = 0; j < 8; ++j) rn[j] = crow[j] * crow[j];
        for (int i = 8; i < DDIM; i += 8)
          for (int j = 0; j < 8; ++j) rn[j] += crow[i + j] * crow[i + j];
        const float Nk =
            ((rn[0] + rn[1]) + (rn[2] + rn[3])) + ((rn[4] + rn[5]) + (rn[6] + rn[7]));

        double p64 = 0.0;
        for (int d = 0; d < DDIM; ++d) p64 += (double)xm[d] * (double)crow[d];
        const float pf = (float)p64;

        const float twop = 2.0f * pf;
        const float t1   = S - twop;
        const float Dv   = t1 + Nk;
        if (Dv < bestD || (Dv == bestD && idx < besti)) { bestD = Dv; besti = idx; }
      }
    }
  }

  // ---- write z_q: 64 rows, coalesced across the wave's 64 tokens ----
  const float* crow = cb + (size_t)besti * DDIM;
  float* ob = out + (size_t)(tk >> 12) * (DDIM * 4096) + (tk & 4095);
  v4f cr[16];
#pragma unroll
  for (int q = 0; q < 16; ++q) cr[q] = *reinterpret_cast<const v4f*>(crow + q * 4);
#pragma unroll
  for (int d = 0; d < DDIM; ++d) ob[(size_t)d * 4096] = cr[d >> 2][d & 3];
}

extern "C" void kernel_launch(void* const* d_in, const int* in_sizes, int n_in,
                              void* d_out, int out_size, void* d_ws, size_t ws_size,
                              hipStream_t stream) {
  const float* ze = (const float*)d_in[0];    // [8,64,64,64]
  const float* cb = (const float*)d_in[1];    // [8192,64]
  float* hn = (float*)d_ws;                                     // 32 KB
  unsigned short* wcb = (unsigned short*)((char*)d_ws + 32768); // 1 MB frag-linear hi
  unsigned* keys = (unsigned*)((char*)d_ws + 32768 + 1048576);  // 4 MB top-2 keys
  float* out = (float*)d_out;

  prep_kernel<<<256, 128, 0, stream>>>(cb, wcb, hn);
  screen_kernel<<<NWG, 256, 0, stream>>>(ze, hn, wcb, keys);
  finish_kernel<<<NTOK / 256, 256, 0, stream>>>(ze, cb, keys, out);
}

// Round 11
// 125.341 us; speedup vs baseline: 1.3491x; 1.3491x over previous
//
#include <hip/hip_runtime.h>
#include <float.h>

// Problem constants (fixed by reference: B=8, D=64, H=64, W=64, K=8192)
constexpr int KCODES = 8192;
constexpr int DDIM   = 64;
constexpr int NTOK   = 32768;
constexpr int MT     = 64;                 // tokens per WG (4 sets x 16)
constexpr int NSETS  = MT / 16;            // 4
constexpr int KC     = 64;                 // codes per chunk
constexpr int NCH    = KCODES / KC;        // 128 chunks
constexpr int CBCHUNK = KC * DDIM * 2;     // 8192 B (64 codes x 64 d x bf16, hi only)

constexpr int RQ    = 4;                   // LDS staging ring depth (per wave)
constexpr int ASLOT = 2048;                // per-wave A-frag bytes per chunk
constexpr int NCELL = 16;                  // 4 waves x 4 quads

typedef short v8s __attribute__((ext_vector_type(8)));
typedef float v4f __attribute__((ext_vector_type(4)));

static __device__ __forceinline__ unsigned short f2bf(float f) {
  union { float f; unsigned u; } v; v.f = f;
  return (unsigned short)((v.u + 0x7fffu + ((v.u >> 16) & 1u)) >> 16);  // RNE
}

// async global->LDS DMA: dest = wave-uniform LDS base + lane*16 (m104);
// source is per-lane. Tracked by vmcnt.
static __device__ __forceinline__ void dma16(const void* g, void* l) {
  __builtin_amdgcn_global_load_lds(
      (const __attribute__((address_space(1))) void*)g,
      (__attribute__((address_space(3))) void*)l, 16, 0, 0);
}

// ---- fused prep: bf16 hi codebook, FRAGMENT-LINEAR for mfma_16x16x32_bf16
// A-operand (A[m=lane&15][k=(lane>>4)*8+j]), + biased half-norms
// hn[k] = 0.5*||c_k||^2 + 2.0 (bias keeps phase-1 scores positive -> fp32
// bit pattern monotone for the packed-key argmin; scores land in [~0.7,~4.5]).
// Per chunk c: byte off = c*8192 + g*2048 + ks*1024 + lane*16 + j*2.
// Grid 256 x 128 threads (2 blocks per chunk): full-device fill.
__global__ __launch_bounds__(128) void prep_kernel(
    const float* __restrict__ cb, unsigned short* __restrict__ wcb,
    float* __restrict__ hn) {
  const int c = blockIdx.x >> 1;            // chunk 0..127
  const int tid = threadIdx.x;
  const int g = ((blockIdx.x & 1) << 1) | (tid >> 6);   // 16-code group 0..3
  const int lane = tid & 63;
  const int quad = lane >> 4, col = lane & 15;
  const int code = c * KC + g * 16 + col;
  const float* src = cb + (size_t)code * DDIM;
  float sq = 0.f;
#pragma unroll
  for (int ks = 0; ks < 2; ++ks) {
    v8s hi;
#pragma unroll
    for (int j = 0; j < 8; ++j) {
      const float x = src[ks * 32 + quad * 8 + j];
      sq += x * x;
      hi[j] = (short)f2bf(x);
    }
    const size_t b0 = ((size_t)c * CBCHUNK + g * 2048 + ks * 1024 + lane * 16) / 2;
    *reinterpret_cast<v8s*>(wcb + b0) = hi;
  }
  sq += __shfl_xor(sq, 16);
  sq += __shfl_xor(sq, 32);
  if (quad == 0) hn[code] = 0.5f * sq + 2.0f;
}

// Phase 1 (SCREEN): round-3/9's measured loop, byte-identical (<60 µs):
//   MT=64, per-wave LDS ring depth 4, 2 dma16/chunk, counted vmcnt(6),
//   hn staged once into LDS, 2 WG/CU. Screening error e = xl.c + xh.cl:
//   RMS ~2.5e-4, |e| <= ~2.8e-3 at 11 sigma. Branchless packed-key top-2
//   per (lane,set) cell: key = (score-bits & ~511) | (it*4 + r); floor
//   quantization <= 512 ulp <= 2.4e-4.
// Phase 2 (R10 lesson: the epilogue was ~29 µs of R3's 84, and 1-token/
//   thread parallelized NOTHING — with candidates spread over 32 slots,
//   nearly every slot has >=1 active lane, so each wave still ran ~30
//   serial fp64 refine bodies):
//   (A) wave 0: per-token smin/cnt/fidx scan (verbatim semantics);
//       cnt==1 -> widx; else push token to LDS worklist.
//   (B) CANDIDATE-PARALLEL refine: one token per 32-lane group (8 groups),
//       ONE candidate slot (c,h) per lane; each lane computes the
//       numpy-fp32-faithful Dv once (pairwise-8 sums, D=fl(fl(S-2p)+N),
//       correctly-rounded-fp64 p); width-32 lexicographic (Dv,idx)
//       shuffle-reduce == serial loop's (Dv<best)||(==&&idx<) tie-break
//       (lexicographic min is associative/commutative; candidates across
//       slots decode to disjoint codes, m1!=m2 within a slot).
//   Fast path proof (unchanged): for any candidate with stored > lim:
//   true > stored - e > smin + 8e-3 - 2.8e-3; smin >= true_min - e -
//   2.4e-4 -> true - true_min > 2e-3 >> numpy ulp noise -> numpy cannot
//   prefer it; a distinct numpy-winner is itself within lim -> cnt >= 2
//   -> refine. Two cells tying exactly at smin both <= lim -> cnt >= 2,
//   so the fast-path fidx is unique.
__global__ __launch_bounds__(256, 2) void vq_kernel(
    const float* __restrict__ ze, const float* __restrict__ cb,
    const float* __restrict__ hn, const unsigned short* __restrict__ wcb,
    float* __restrict__ out) {
  // LDS map: [0,32768) per-wave staging ring; [32768,65536) static hn copy.
  // Epilogue arrays alias the ring after drain + barrier.
  __shared__ __align__(16) char smem[65536];

  const int tid = threadIdx.x, lane = tid & 63, wv = tid >> 6;
  const int col = lane & 15, quad = lane >> 4;
  const int t0 = blockIdx.x * MT;
  const int bb = t0 >> 12, hw0 = t0 & 4095;   // 4096 % 64 == 0: one batch per WG
  const float* zb = ze + (size_t)bb * (DDIM * 4096) + hw0;

  // ---- one-time hn -> LDS copy (32 KB, 8 x float4 per thread) ----
  {
    v4f* dst = (v4f*)(smem + 32768);
    const v4f* src = (const v4f*)hn;
#pragma unroll
    for (int i = 0; i < 8; ++i) dst[tid + i * 256] = src[tid + i * 256];
  }

  // ---- B-frags: 4 sets x 16 tokens, negated bf16-hi, in registers.
  // B[k=(lane>>4)*8+j][n=lane&15]; token = s*16 + col; d = ks*32 + quad*8 + j.
  v8s nxh[NSETS][2];
#pragma unroll
  for (int s = 0; s < NSETS; ++s) {
    const int mtok = s * 16 + col;
#pragma unroll
    for (int ks = 0; ks < 2; ++ks) {
#pragma unroll
      for (int j = 0; j < 8; ++j) {
        const int d = ks * 32 + quad * 8 + j;
        nxh[s][ks][j] = (short)f2bf(-zb[(size_t)d * 4096 + mtok]);
      }
    }
  }

  char* wbase = smem + wv * (RQ * ASLOT);
  const char* wsrc = (const char*)wcb + wv * 2048 + lane * 16;
  const char* hns  = smem + 32768 + wv * 64 + quad * 16;  // this cell's hv

  auto stage = [&](int chunk, int slot) {
    const char* src = wsrc + (size_t)chunk * CBCHUNK;
    char* dst = wbase + slot * ASLOT;
    dma16(src, dst);
    dma16(src + 1024, dst + 1024);
  };

  unsigned m1[NSETS] = {0xFFFFFFFFu, 0xFFFFFFFFu, 0xFFFFFFFFu, 0xFFFFFFFFu};
  unsigned m2[NSETS] = {0xFFFFFFFFu, 0xFFFFFFFFu, 0xFFFFFFFFu, 0xFFFFFFFFu};

  auto compute = [&](const v8s (&A)[2], const v4f hv, int it) {
    const unsigned base9 = (unsigned)(it * 4);   // 9-bit cell-local index base
#pragma unroll
    for (int s = 0; s < NSETS; ++s) {            // 4 independent MFMA chains
      v4f acc = __builtin_amdgcn_mfma_f32_16x16x32_bf16(A[0], nxh[s][0], hv, 0, 0, 0);
      acc = __builtin_amdgcn_mfma_f32_16x16x32_bf16(A[1], nxh[s][1], acc, 0, 0, 0);
      unsigned k0 = (__float_as_uint(acc[0]) & ~511u) | (base9 + 0);
      unsigned k1 = (__float_as_uint(acc[1]) & ~511u) | (base9 + 1);
      unsigned k2 = (__float_as_uint(acc[2]) & ~511u) | (base9 + 2);
      unsigned k3 = (__float_as_uint(acc[3]) & ~511u) | (base9 + 3);
      const unsigned km = min(min(k0, k1), min(k2, k3));
      const unsigned old1 = m1[s];
      m1[s] = min(old1, km);
      m2[s] = min(m2[s], max(old1, km));   // branchless 2nd-best
    }
  };

  // hn LDS writes visible to all waves before any in-loop hv read.
  __syncthreads();

  // ---- airtight vmcnt ledger: drain prologue loads before first stage.
  asm volatile("s_waitcnt vmcnt(0)" ::: "memory");
  __builtin_amdgcn_sched_barrier(0);

#pragma unroll
  for (int r = 0; r < RQ; ++r) stage(r, r);   // 8 DMAs in flight (chunks 0..3)

  int sl = 0;
  for (int it = 0; it < NCH; ++it) {
    // Chunk it's 2 DMAs landed once <= 6 remain outstanding (in-order).
    asm volatile("s_waitcnt vmcnt(6)" ::: "memory");
    __builtin_amdgcn_sched_barrier(0);

    v8s A[2]; v4f hv;
    {
      const char* b = wbase + sl * ASLOT;
      A[0] = *reinterpret_cast<const v8s*>(b + lane * 16);
      A[1] = *reinterpret_cast<const v8s*>(b + 1024 + lane * 16);
      hv   = *reinterpret_cast<const v4f*>(hns + (size_t)it * 256);
    }
    compute(A, hv, it);

    // ds_reads of this slot fully retired before the DMA overwrite lands.
    asm volatile("s_waitcnt lgkmcnt(0)" ::: "memory");
    __builtin_amdgcn_sched_barrier(0);
    stage((it + RQ) & (NCH - 1), sl);   // tail wrap: redundant, never read
    sl = (sl == RQ - 1) ? 0 : sl + 1;
  }

  // Drain in-flight DMAs, then all waves quiesce before aliasing LDS.
  asm volatile("s_waitcnt vmcnt(0)" ::: "memory");
  __syncthreads();

  unsigned (*c_k1)[MT] = (unsigned (*)[MT])(smem);          // 4 KB
  unsigned (*c_k2)[MT] = (unsigned (*)[MT])(smem + 4096);   // 4 KB
  int*   widx  = (int*)(smem + 8192);                       // 256 B
  float* limv  = (float*)(smem + 8448);                     // 256 B
  int*   rlist = (int*)(smem + 8704);                       // 256 B
  int*   rcnt  = (int*)(smem + 8960);                       // 4 B

  // ---- surface per-cell top-2 keys (cell = wv*4+quad) ----
  {
    const int cell = wv * 4 + quad;
#pragma unroll
    for (int s = 0; s < NSETS; ++s) {
      const int m = s * 16 + col;
      c_k1[cell][m] = m1[s];
      c_k2[cell][m] = m2[s];
    }
  }
  if (tid == 0) *rcnt = 0;
  __syncthreads();

  // ---- step A: wave 0 scans per-token smin/cnt; fast path or worklist ----
  if (tid < MT) {
    const int m = tid;
    float smin = FLT_MAX; int fidx = 0x7fffffff;
#pragma unroll
    for (int c = 0; c < NCELL; ++c) {
      const unsigned Kc = c_k1[c][m];
      const float a = __uint_as_float(Kc & ~511u);
      if (a < smin) {
        smin = a;
        fidx = (int)((Kc & 511u) >> 2) * KC + (c >> 2) * 16 + (c & 3) * 4 +
               (int)(Kc & 3u);
      }
    }
    const float lim = smin + 8e-3f;   // covers 2*e_screen(2.8e-3) + key floor
                                      // 2.4e-4 + numpy noise, ~1.4x slack
    int cnt = 0;
#pragma unroll
    for (int c = 0; c < NCELL; ++c) {
      cnt += (__uint_as_float(c_k1[c][m] & ~511u) <= lim);
      cnt += (__uint_as_float(c_k2[c][m] & ~511u) <= lim);
    }
    if (cnt == 1) {
      widx[m] = fidx;   // unique in-margin candidate == numpy argmin
    } else {
      limv[m] = lim;
      const int pos = atomicAdd(rcnt, 1);
      rlist[pos] = m;
    }
  }
  __syncthreads();

  // ---- step B: candidate-parallel refine: one token per 32-lane group,
  // one candidate slot (c,h) per lane, lexicographic (Dv,idx) reduce ----
  {
    const int grp = tid >> 5, gl = tid & 31;
    const int nref = *rcnt;
    for (int i = grp; i < nref; i += 8) {
#pragma clang fp contract(off)   // numpy: separate mul then add; no FMA
      const int m = rlist[i];
      const float lim = limv[m];
      const int c = gl >> 1, h = gl & 1;
      const unsigned Kc = h ? c_k2[c][m] : c_k1[c][m];
      const float sp = __uint_as_float(Kc & ~511u);

      const float* xz = zb + m;
      float xm[DDIM];
      for (int d = 0; d < DDIM; ++d) xm[d] = xz[(size_t)d * 4096];  // broadcast

      float r[8];
      for (int j = 0; j < 8; ++j) r[j] = xm[j] * xm[j];
      for (int q = 8; q < DDIM; q += 8)
        for (int j = 0; j < 8; ++j) r[j] += xm[q + j] * xm[q + j];
      const float S = ((r[0] + r[1]) + (r[2] + r[3])) + ((r[4] + r[5]) + (r[6] + r[7]));

      float Dv = FLT_MAX;
      int idx = 0x7fffffff;
      if (sp <= lim) {
        idx = (int)((Kc & 511u) >> 2) * KC + (c >> 2) * 16 + (c & 3) * 4 +
              (int)(Kc & 3u);
        const float* crow = cb + (size_t)idx * DDIM;
        float rn[8];
        for (int j = 0; j < 8; ++j) rn[j] = crow[j] * crow[j];
        for (int q = 8; q < DDIM; q += 8)
          for (int j = 0; j < 8; ++j) rn[j] += crow[q + j] * crow[q + j];
        const float Nk =
            ((rn[0] + rn[1]) + (rn[2] + rn[3])) + ((rn[4] + rn[5]) + (rn[6] + rn[7]));

        double p64 = 0.0;
        for (int d = 0; d < DDIM; ++d) p64 += (double)xm[d] * (double)crow[d];
        const float pf = (float)p64;

        const float twop = 2.0f * pf;
        const float t1   = S - twop;
        Dv = t1 + Nk;
      }
#pragma unroll
      for (int off = 1; off < 32; off <<= 1) {
        const float oD = __shfl_xor(Dv, off, 32);
        const int   oI = __shfl_xor(idx, off, 32);
        if (oD < Dv || (oD == Dv && oI < idx)) { Dv = oD; idx = oI; }
      }
      if (gl == 0) widx[m] = idx;
    }
  }
  __syncthreads();

  // ---- step C: gather winners, write z_q (64-lane coalesced rows) ----
  {
    const int m = tid & 63, dg = tid >> 6;    // dg 0..3
    const int wi = widx[m];
    const float* crow = cb + (size_t)wi * DDIM;
    float* ob = out + (size_t)bb * (DDIM * 4096) + hw0;
#pragma unroll
    for (int p = 0; p < 16; ++p) {
      const int d = dg * 16 + p;
      ob[(size_t)d * 4096 + m] = crow[d];
    }
  }
}

extern "C" void kernel_launch(void* const* d_in, const int* in_sizes, int n_in,
                              void* d_out, int out_size, void* d_ws, size_t ws_size,
                              hipStream_t stream) {
  const float* ze = (const float*)d_in[0];    // [8,64,64,64]
  const float* cb = (const float*)d_in[1];    // [8192,64]
  float* hn = (float*)d_ws;                                     // 32 KB
  unsigned short* wcb = (unsigned short*)((char*)d_ws + 32768); // 1 MB frag-linear hi
  float* out = (float*)d_out;

  prep_kernel<<<256, 128, 0, stream>>>(cb, wcb, hn);
  vq_kernel<<<NTOK / MT, 256, 0, stream>>>(ze, cb, hn, wcb, out);
}